// Round 1
// 703.053 us; speedup vs baseline: 1.1789x; 1.1789x over previous
//
#include <hip/hip_runtime.h>
#include <float.h>

#define D_DIM 512
#define NC    64
#define NB    200000
#define BS_N  2048
#define NCL   100
#define TK    64
#define CAP   2048      // candidate capacity per concept (bin == B)

// d_out float offsets
#define O_ORIG 0          // 2048*100
#define O_YPRED 204800    // 2048*100
#define O_L1   409600
#define O_L2   409601
#define O_NORM 409602
#define O_CPRED 409603    // 2048*64

// ws float offsets
#define W_GRAM  0         // 4096
#define W_GINV  4096      // 4096
#define W_U     8192      // 6400
#define W_H     14592     // 6400 (unused now, kept for layout stability)
#define W_Q     20992     // 200000
#define W_MIN   220992    // 64 (ordered-uint min per concept)
#define W_MAX   221056    // 64
#define W_BIN   221120    // 64
#define W_NBEL  221184    // 64
#define W_CCNT  221248    // 64
#define W_PSUM  221312    // 64
#define W_HIST  221376    // 64*1024
#define W_CANDV 286912    // 64*2048
#define W_CANDD 417984    // 131072
#define W_PACKA 549056    // 32768 bf16 = 16384 floats (C in A-frag layout)
#define W_PACKB 565440    // 90112 bf16 = 45056 floats ([C|W] in A-frag layout)
#define W_S     610496    // 64*200000 floats

typedef __attribute__((ext_vector_type(8))) short bf16x8;
typedef __attribute__((ext_vector_type(4))) float f32x4;

__device__ inline unsigned f2ord(float f) {
    unsigned u = __float_as_uint(f);
    return (u & 0x80000000u) ? ~u : (u | 0x80000000u);
}
__device__ inline float ord2f(unsigned u) {
    return (u & 0x80000000u) ? __uint_as_float(u & 0x7fffffffu) : __uint_as_float(~u);
}
__device__ inline short f2bf(float f) {   // RNE fp32 -> bf16
    unsigned u = __float_as_uint(f);
    u += 0x7FFFu + ((u >> 16) & 1u);
    return (short)(u >> 16);
}

// =================================================================================
// k1: gram (blocks 0..15) + U (16..40) + pack (41..280) + hist-zero (281..344)
//     + small inits (345). All independent; replaces 3 kernels + 5 memsets.
// =================================================================================
__global__ __launch_bounds__(256) void k1_setup(
    const float* __restrict__ C, const float* __restrict__ W,
    short* __restrict__ PA, short* __restrict__ PB,
    float* __restrict__ gram, float* __restrict__ U,
    unsigned* __restrict__ mnord, unsigned* __restrict__ mxord,
    unsigned* __restrict__ hist, int* __restrict__ ccnt, float* __restrict__ psum)
{
    int bid = blockIdx.x, t = threadIdx.x;
    if (bid < 16) {                       // gram = C^T C, one (i,j) per thread
        int idx = bid * 256 + t;          // 0..4095
        int i = idx >> 6, j = idx & 63;
        float s = 0.f;
        for (int k = 0; k < D_DIM; ++k) s = fmaf(C[k*NC + i], C[k*NC + j], s);
        gram[idx] = s;
    } else if (bid < 41) {                // U = C^T W, one (i,j) per thread
        int idx = (bid - 16) * 256 + t;   // 0..6399
        int i = idx / 100, j = idx - i * 100;
        float s = 0.f;
        for (int k = 0; k < D_DIM; ++k) s = fmaf(C[k*NC + i], W[k*NCL + j], s);
        U[idx] = s;
    } else if (bid < 281) {               // pack C / [C|W] into MFMA A-frag bf16
        int b = bid - 41;                 // 0..239
        #pragma unroll
        for (int rep = 0; rep < 2; ++rep) {
            int idx = t * 2 + rep;        // 0..511 within tile
            int lane = idx >> 3, j = idx & 7;
            if (b < 64) {                 // score A: 16 kt x 4 ci
                int kt = b >> 2, ci = b & 3;
                int k = kt * 32 + (lane >> 4) * 8 + j;
                int col = ci * 16 + (lane & 15);
                PA[b * 512 + idx] = f2bf(C[k * NC + col]);
            } else {                      // ecw A: 16 kt x 11 ci (64 C + 100 W + 12 pad)
                int bb = b - 64;
                int kt = bb / 11, ci = bb % 11;
                int k = kt * 32 + (lane >> 4) * 8 + j;
                int col = ci * 16 + (lane & 15);
                float v = 0.f;
                if (col < 64) v = C[k * NC + col];
                else if (col < 164) v = W[k * NCL + (col - 64)];
                PB[bb * 512 + idx] = f2bf(v);
            }
        }
    } else if (bid < 345) {               // zero hist (64 blocks x 1024)
        int base = (bid - 281) * 1024;
        #pragma unroll
        for (int r = 0; r < 4; ++r) hist[base + r * 256 + t] = 0u;
    } else {                              // small per-concept inits
        if (t < 64) {
            mnord[t] = 0xFFFFFFFFu;
            mxord[t] = 0u;
            ccnt[t]  = 0;
            psum[t]  = 0.f;
        }
    }
}

// =================================================================================
// k2: invert (block 0, in-place GJ in 17 KB LDS) + scalars (block 1)
//     + ecw (blocks 2..17) + score (blocks 18..1580).
//     Tiny serial work starts first and hides under the memory-bound score stream.
// =================================================================================
__global__ __launch_bounds__(256) void k2_main(
    const float* __restrict__ E, const float* __restrict__ Bk,
    const short* __restrict__ PA, const short* __restrict__ PB,
    const float* __restrict__ gram, float* __restrict__ ginv,
    float* __restrict__ out3, float* __restrict__ T, float* __restrict__ O,
    float* __restrict__ S, float* __restrict__ Q,
    unsigned* __restrict__ mnord, unsigned* __restrict__ mxord)
{
    __shared__ float smem[64 * 65 + 64];   // 16.9 KB union: invert | scalars | score lmn/lmx
    int bid = blockIdx.x, t = threadIdx.x;

    if (bid == 0) {
        // ---- in-place Gauss-Jordan inversion of gram (SPD, well-conditioned) ----
        float (*A)[65] = (float(*)[65])smem;
        float* m = smem + 64 * 65;
        for (int idx = t; idx < 4096; idx += 256) A[idx >> 6][idx & 63] = gram[idx];
        __syncthreads();
        for (int k = 0; k < 64; ++k) {
            float d = 1.0f / A[k][k];
            if (t < 64) m[t] = A[t][k];            // capture column k
            __syncthreads();
            if (t < 64 && t != k) A[k][t] *= d;    // scale row k (j != k)
            __syncthreads();
            for (int idx = t; idx < 4096; idx += 256) {
                int i = idx >> 6, j = idx & 63;
                if (i != k && j != k) A[i][j] = fmaf(-m[i], A[k][j], A[i][j]);
            }
            if (t < 64) {                          // column k + diagonal (disjoint addrs)
                if (t != k) A[t][k] = -m[t] * d;
                else        A[k][k] = d;
            }
            __syncthreads();
        }
        for (int idx = t; idx < 4096; idx += 256) ginv[idx] = A[idx >> 6][idx & 63];
    } else if (bid == 1) {
        // ---- L_sparse_2, norm_metrics, zero L1 accumulator ----
        float* ra = smem; float* rd = smem + 256;
        float sa = 0.f, sd = 0.f;
        for (int idx = t; idx < NC * NC; idx += 256) {
            float g = gram[idx];
            sa += g;
            if (idx % (NC + 1) == 0) sd += g;
        }
        ra[t] = sa; rd[t] = sd;
        __syncthreads();
        for (int s2 = 128; s2 > 0; s2 >>= 1) {
            if (t < s2) { ra[t] += ra[t + s2]; rd[t] += rd[t + s2]; }
            __syncthreads();
        }
        if (t == 0) {
            out3[0] = 0.f;
            out3[1] = (ra[0] - rd[0]) * (1.0f / 4096.0f);
            out3[2] = rd[0] * (1.0f / 4096.0f);
        }
    } else if (bid < 18) {
        // ---- ecw: fused E@[C|W] via bf16 MFMA -> concept_pred (T), orig_pred (O) ----
        int eb = bid - 2;
        int wave = t >> 6, lane = t & 63;
        int quad = lane >> 4, l16 = lane & 15;
        int rbase = eb * 128 + wave * 32;
        int row0 = rbase + l16, row1 = rbase + 16 + l16;
        const float* p0 = E + (size_t)row0 * D_DIM + quad * 8;
        const float* p1 = E + (size_t)row1 * D_DIM + quad * 8;

        f32x4 acc[11][2];
        #pragma unroll
        for (int ci = 0; ci < 11; ++ci) { acc[ci][0] = 0.f; acc[ci][1] = 0.f; }

        for (int kt = 0; kt < 16; ++kt) {
            float4 a0 = *(const float4*)(p0 + kt*32);
            float4 b0 = *(const float4*)(p0 + kt*32 + 4);
            float4 a1 = *(const float4*)(p1 + kt*32);
            float4 b1 = *(const float4*)(p1 + kt*32 + 4);
            bf16x8 bf0 = { f2bf(a0.x), f2bf(a0.y), f2bf(a0.z), f2bf(a0.w),
                           f2bf(b0.x), f2bf(b0.y), f2bf(b0.z), f2bf(b0.w) };
            bf16x8 bf1 = { f2bf(a1.x), f2bf(a1.y), f2bf(a1.z), f2bf(a1.w),
                           f2bf(b1.x), f2bf(b1.y), f2bf(b1.z), f2bf(b1.w) };
            #pragma unroll
            for (int ci = 0; ci < 11; ++ci) {
                bf16x8 af = *(const bf16x8*)(PB + ((kt*11 + ci)*64 + lane)*8);
                acc[ci][0] = __builtin_amdgcn_mfma_f32_16x16x32_bf16(af, bf0, acc[ci][0], 0, 0, 0);
                acc[ci][1] = __builtin_amdgcn_mfma_f32_16x16x32_bf16(af, bf1, acc[ci][1], 0, 0, 0);
            }
        }
        #pragma unroll
        for (int ci = 0; ci < 11; ++ci) {
            #pragma unroll
            for (int j = 0; j < 4; ++j) {
                int col = ci*16 + quad*4 + j;
                if (col < 64) {
                    T[row0*NC + col] = acc[ci][0][j];
                    T[row1*NC + col] = acc[ci][1][j];
                } else if (col < 164) {
                    O[row0*NCL + (col-64)] = acc[ci][0][j];
                    O[row1*NCL + (col-64)] = acc[ci][1][j];
                }
            }
        }
    } else {
        // ---- score: S[c][r] = q[r] - 2 * (C^T B^T)[c][r] via bf16 MFMA ----
        int sb = bid - 18;
        unsigned* lmn = (unsigned*)smem;
        unsigned* lmx = lmn + 64;
        int wave = t >> 6, lane = t & 63;
        int quad = lane >> 4, l16 = lane & 15;
        if (t < 64) { lmn[t] = 0xFFFFFFFFu; lmx[t] = 0u; }
        __syncthreads();

        int rbase = sb * 128 + wave * 32;
        int row0 = rbase + l16, row1 = rbase + 16 + l16;
        bool v0 = row0 < NB, v1 = row1 < NB;
        int r0c = v0 ? row0 : (NB-1), r1c = v1 ? row1 : (NB-1);
        const float* p0 = Bk + (size_t)r0c * D_DIM + quad * 8;
        const float* p1 = Bk + (size_t)r1c * D_DIM + quad * 8;

        f32x4 acc[4][2];
        #pragma unroll
        for (int ci = 0; ci < 4; ++ci) { acc[ci][0] = 0.f; acc[ci][1] = 0.f; }
        float q0 = 0.f, q1 = 0.f;

        for (int kt = 0; kt < 16; ++kt) {
            float4 a0 = *(const float4*)(p0 + kt*32);
            float4 b0 = *(const float4*)(p0 + kt*32 + 4);
            float4 a1 = *(const float4*)(p1 + kt*32);
            float4 b1 = *(const float4*)(p1 + kt*32 + 4);
            q0 = fmaf(a0.x,a0.x, fmaf(a0.y,a0.y, fmaf(a0.z,a0.z, fmaf(a0.w,a0.w, q0))));
            q0 = fmaf(b0.x,b0.x, fmaf(b0.y,b0.y, fmaf(b0.z,b0.z, fmaf(b0.w,b0.w, q0))));
            q1 = fmaf(a1.x,a1.x, fmaf(a1.y,a1.y, fmaf(a1.z,a1.z, fmaf(a1.w,a1.w, q1))));
            q1 = fmaf(b1.x,b1.x, fmaf(b1.y,b1.y, fmaf(b1.z,b1.z, fmaf(b1.w,b1.w, q1))));
            bf16x8 bf0 = { f2bf(a0.x), f2bf(a0.y), f2bf(a0.z), f2bf(a0.w),
                           f2bf(b0.x), f2bf(b0.y), f2bf(b0.z), f2bf(b0.w) };
            bf16x8 bf1 = { f2bf(a1.x), f2bf(a1.y), f2bf(a1.z), f2bf(a1.w),
                           f2bf(b1.x), f2bf(b1.y), f2bf(b1.z), f2bf(b1.w) };
            #pragma unroll
            for (int ci = 0; ci < 4; ++ci) {
                bf16x8 af = *(const bf16x8*)(PA + ((kt*4 + ci)*64 + lane)*8);
                acc[ci][0] = __builtin_amdgcn_mfma_f32_16x16x32_bf16(af, bf0, acc[ci][0], 0, 0, 0);
                acc[ci][1] = __builtin_amdgcn_mfma_f32_16x16x32_bf16(af, bf1, acc[ci][1], 0, 0, 0);
            }
        }
        // q: reduce partial sums across quads (same l16)
        q0 += __shfl_xor(q0, 16); q0 += __shfl_xor(q0, 32);
        q1 += __shfl_xor(q1, 16); q1 += __shfl_xor(q1, 32);
        if (quad == 0) {
            if (v0) Q[row0] = q0;
            if (v1) Q[row1] = q1;
        }
        #pragma unroll
        for (int ci = 0; ci < 4; ++ci) {
            #pragma unroll
            for (int j = 0; j < 4; ++j) {
                int c = ci*16 + quad*4 + j;
                float s0 = q0 - 2.0f * acc[ci][0][j];
                float s1 = q1 - 2.0f * acc[ci][1][j];
                if (v0) S[(size_t)c*NB + row0] = s0;
                if (v1) S[(size_t)c*NB + row1] = s1;
                float mnv = fminf(v0 ? s0 : FLT_MAX,  v1 ? s1 : FLT_MAX);
                float mxv = fmaxf(v0 ? s0 : -FLT_MAX, v1 ? s1 : -FLT_MAX);
                #pragma unroll
                for (int o = 1; o < 16; o <<= 1) {
                    mnv = fminf(mnv, __shfl_xor(mnv, o));
                    mxv = fmaxf(mxv, __shfl_xor(mxv, o));
                }
                if (l16 == 0) {
                    atomicMin(&lmn[c], f2ord(mnv));
                    atomicMax(&lmx[c], f2ord(mxv));
                }
            }
        }
        __syncthreads();
        if (t < 64) {
            atomicMin(&mnord[t], lmn[t]);
            atomicMax(&mxord[t], lmx[t]);
        }
    }
}

// =================================================================================
// k3: ypred with inline H (blocks 0..63) + hist (blocks 64..3199).
//     h_kernel eliminated: H = Ginv@U recomputed per ypred block in LDS (26 MFLOP total).
// =================================================================================
__global__ __launch_bounds__(256) void k3_ph(
    const float* __restrict__ T, const float* __restrict__ ginv,
    const float* __restrict__ U, float* __restrict__ Y,
    const float* __restrict__ S, const unsigned* __restrict__ mnord,
    const unsigned* __restrict__ mxord, unsigned* __restrict__ hist)
{
    __shared__ float smem[6400];           // H (25.6 KB) | hist bins (4 KB)
    int bid = blockIdx.x, t = threadIdx.x;
    if (bid < 64) {
        // H[k][c] = sum_l Ginv[k][l] * U[l][c]
        for (int idx = t; idx < 6400; idx += 256) {
            int k = idx / 100, c = idx - k * 100;
            float s = 0.f;
            #pragma unroll 8
            for (int l = 0; l < NC; ++l) s = fmaf(ginv[k*NC + l], U[l*NCL + c], s);
            smem[idx] = s;
        }
        __syncthreads();
        // Y rows bid*32 .. bid*32+31
        for (int o = t; o < 3200; o += 256) {
            int r = o / 100, c = o - r * 100;
            int row = bid * 32 + r;
            float s = 0.f;
            #pragma unroll 8
            for (int k = 0; k < NC; ++k) s = fmaf(T[row*NC + k], smem[k*100 + c], s);
            Y[row*NCL + c] = s;
        }
    } else {
        int h = bid - 64;
        int c = h & 63, chunk = h >> 6;    // 64 concepts x 49 chunks
        unsigned* hh = (unsigned*)smem;
        for (int i = t; i < 1024; i += 256) hh[i] = 0u;
        float mnf = ord2f(mnord[c]);
        float mxf = ord2f(mxord[c]);
        float invw = (mxf > mnf) ? 1024.0f / (mxf - mnf) : 0.f;
        __syncthreads();
        const float4* s4 = (const float4*)(S + (size_t)c * NB);
        int base = chunk * 1024;
        #pragma unroll
        for (int j = 0; j < 4; ++j) {
            int idx = base + j*256 + t;
            if (idx < NB/4) {
                float4 v = s4[idx];
                float vv[4] = {v.x, v.y, v.z, v.w};
                #pragma unroll
                for (int e = 0; e < 4; ++e) {
                    int b = (int)((vv[e] - mnf) * invw);
                    b = b < 0 ? 0 : (b > 1023 ? 1023 : b);
                    atomicAdd(&hh[b], 1u);
                }
            }
        }
        __syncthreads();
        for (int i = t; i < 1024; i += 256)
            if (hh[i]) atomicAdd(&hist[c*1024 + i], hh[i]);
    }
}

// ---------------- scan: per-concept threshold bin ----------------
__global__ void scan_kernel(const unsigned* __restrict__ hist,
                            int* __restrict__ binB, int* __restrict__ nbel) {
    __shared__ unsigned h[1024];
    int c = blockIdx.x, t = threadIdx.x;
    for (int i = t; i < 1024; i += 256) h[i] = hist[c*1024 + i];
    __syncthreads();
    if (t == 0) {
        unsigned cum = 0; int B = 1023; unsigned below = 0;
        for (int b = 0; b < 1024; ++b) {
            unsigned hb = h[b];
            if (cum + hb >= TK) { B = b; below = cum; break; }
            cum += hb;
        }
        binB[c] = B;
        nbel[c] = (int)below;
    }
}

// ---------------- collect: sum dots below B, gather bin-B candidates ----------------
__global__ void collect_kernel(const float* __restrict__ S, const float* __restrict__ Q,
                               const unsigned* __restrict__ mn_ord, const unsigned* __restrict__ mx_ord,
                               const int* __restrict__ binB,
                               int* __restrict__ ccnt, float* __restrict__ candv,
                               float* __restrict__ candd, float* __restrict__ psum) {
    __shared__ float red[256];
    int c = blockIdx.y, t = threadIdx.x;
    float mnf = ord2f(mn_ord[c]);
    float mxf = ord2f(mx_ord[c]);
    float invw = (mxf > mnf) ? 1024.0f / (mxf - mnf) : 0.f;
    int B = binB[c];
    const float4* s4 = (const float4*)(S + (size_t)c * NB);
    int base = blockIdx.x * 1024;
    float dsum = 0.f;
    #pragma unroll
    for (int j = 0; j < 4; ++j) {
        int idx = base + j*256 + t;
        if (idx < NB/4) {
            float4 v = s4[idx];
            float vv[4] = {v.x, v.y, v.z, v.w};
            #pragma unroll
            for (int e = 0; e < 4; ++e) {
                int b = (int)((vv[e] - mnf) * invw);
                b = b < 0 ? 0 : (b > 1023 ? 1023 : b);
                if (b < B) {
                    dsum += (Q[idx*4 + e] - vv[e]) * 0.5f;
                } else if (b == B) {
                    int p = atomicAdd(&ccnt[c], 1);
                    if (p < CAP) {
                        candv[c*CAP + p] = vv[e];
                        candd[c*CAP + p] = (Q[idx*4 + e] - vv[e]) * 0.5f;
                    }
                }
            }
        }
    }
    red[t] = dsum;
    __syncthreads();
    for (int s2 = 128; s2 > 0; s2 >>= 1) {
        if (t < s2) red[t] += red[t+s2];
        __syncthreads();
    }
    if (t == 0 && red[0] != 0.f) atomicAdd(&psum[c], red[0]);
}

// ---------------- final: exact top among bin-B candidates ----------------
__global__ void final_kernel(const int* __restrict__ binB, const int* __restrict__ nbel,
                             const int* __restrict__ ccnt, const float* __restrict__ candv,
                             const float* __restrict__ candd, const float* __restrict__ psum,
                             float* __restrict__ out_l1) {
    __shared__ float v[CAP];
    __shared__ float dd[CAP];
    int c = blockIdx.x, t = threadIdx.x;   // 64 threads = 1 wave
    int M = ccnt[c]; if (M > CAP) M = CAP;
    int r = TK - nbel[c]; if (r > M) r = M;
    for (int i = t; i < M; i += 64) { v[i] = candv[c*CAP + i]; dd[i] = candd[c*CAP + i]; }
    __syncthreads();
    float sum = 0.f;
    for (int j = 0; j < r; ++j) {
        float bv = FLT_MAX; int bi = -1;
        for (int i = t; i < M; i += 64)
            if (v[i] < bv) { bv = v[i]; bi = i; }
        #pragma unroll
        for (int o = 32; o > 0; o >>= 1) {
            float ov = __shfl_down(bv, o);
            int   oi = __shfl_down(bi, o);
            if (ov < bv) { bv = ov; bi = oi; }
        }
        bi = __shfl(bi, 0);
        if (t == 0 && bi >= 0) { sum += dd[bi]; v[bi] = FLT_MAX; }
        __syncthreads();
    }
    if (t == 0) atomicAdd(out_l1, (sum + psum[c]) * (1.0f/4096.0f));
}

extern "C" void kernel_launch(void* const* d_in, const int* in_sizes, int n_in,
                              void* d_out, int out_size, void* d_ws, size_t ws_size,
                              hipStream_t stream) {
    const float* C  = (const float*)d_in[0];   // (512, 64)
    const float* E  = (const float*)d_in[1];   // (2048, 512)
    const float* Bk = (const float*)d_in[2];   // (200000, 512)
    const float* W  = (const float*)d_in[3];   // (512, 100)
    float* out = (float*)d_out;
    float* ws  = (float*)d_ws;

    float*    gram  = ws + W_GRAM;
    float*    ginv  = ws + W_GINV;
    float*    U     = ws + W_U;
    float*    Q     = ws + W_Q;
    unsigned* mnord = (unsigned*)(ws + W_MIN);
    unsigned* mxord = (unsigned*)(ws + W_MAX);
    int*      binB  = (int*)(ws + W_BIN);
    int*      nbel  = (int*)(ws + W_NBEL);
    int*      ccnt  = (int*)(ws + W_CCNT);
    float*    psum  = ws + W_PSUM;
    unsigned* hist  = (unsigned*)(ws + W_HIST);
    float*    candv = ws + W_CANDV;
    float*    candd = ws + W_CANDD;
    short*    PA    = (short*)(ws + W_PACKA);
    short*    PB    = (short*)(ws + W_PACKB);
    float*    S     = ws + W_S;

    // 6 dispatches total (was 18: 5 memsets + 13 kernels)
    k1_setup<<<346, 256, 0, stream>>>(C, W, PA, PB, gram, U, mnord, mxord, hist, ccnt, psum);
    k2_main <<<1581, 256, 0, stream>>>(E, Bk, PA, PB, gram, ginv, out + O_L1,
                                       out + O_CPRED, out + O_ORIG, S, Q, mnord, mxord);
    k3_ph   <<<3200, 256, 0, stream>>>(out + O_CPRED, ginv, U, out + O_YPRED,
                                       S, mnord, mxord, hist);
    scan_kernel   <<<64, 256, 0, stream>>>(hist, binB, nbel);
    collect_kernel<<<dim3(49, 64), 256, 0, stream>>>(S, Q, mnord, mxord, binB, ccnt, candv, candd, psum);
    final_kernel  <<<NC, 64, 0, stream>>>(binB, nbel, ccnt, candv, candd, psum, out + O_L1);
}

// Round 4
// 660.321 us; speedup vs baseline: 1.2552x; 1.0647x over previous
//
#include <hip/hip_runtime.h>
#include <float.h>

#define D_DIM 512
#define NC    64
#define NB    200000
#define BS_N  2048
#define NCL   100
#define TK    64
#define CAP   2048      // candidate capacity per concept (bin == B)

// d_out float offsets
#define O_ORIG 0          // 2048*100
#define O_YPRED 204800    // 2048*100
#define O_L1   409600
#define O_L2   409601
#define O_NORM 409602
#define O_CPRED 409603    // 2048*64

// ws float offsets
#define W_GRAM  0         // 4096
#define W_GINV  4096      // 4096
#define W_U     8192      // 6400
#define W_H     14592     // 6400
#define W_Q     20992     // 200000
#define W_MIN   220992    // 64 (ordered-uint min per concept)
#define W_MAX   221056    // 64
#define W_DONE  221120    // 64 (unused this round)
#define W_NBEL  221184    // 64 (unused)
#define W_CCNT  221248    // 64
#define W_PSUM  221312    // 64
#define W_HIST  221376    // 64*1024
#define W_CANDV 286912    // 64*2048
#define W_CANDD 417984    // 131072
#define W_PACKA 549056    // 32768 bf16 = 16384 floats (C in A-frag layout)
#define W_PACKB 565440    // 90112 bf16 = 45056 floats ([C|W] in A-frag layout)
#define W_S     610496    // 64*200000 floats

typedef __attribute__((ext_vector_type(8))) short bf16x8;
typedef __attribute__((ext_vector_type(4))) float f32x4;

__device__ inline unsigned f2ord(float f) {
    unsigned u = __float_as_uint(f);
    return (u & 0x80000000u) ? ~u : (u | 0x80000000u);
}
__device__ inline float ord2f(unsigned u) {
    return (u & 0x80000000u) ? __uint_as_float(u & 0x7fffffffu) : __uint_as_float(~u);
}
__device__ inline short f2bf(float f) {   // RNE fp32 -> bf16
    unsigned u = __float_as_uint(f);
    u += 0x7FFFu + ((u >> 16) & 1u);
    return (short)(u >> 16);
}

// =================================================================================
// k1: gram (blocks 0..15) + U (16..40) + pack (41..280) + hist-zero (281..344)
//     + small inits (345).
// =================================================================================
__global__ __launch_bounds__(256) void k1_setup(
    const float* __restrict__ C, const float* __restrict__ W,
    short* __restrict__ PA, short* __restrict__ PB,
    float* __restrict__ gram, float* __restrict__ U,
    unsigned* __restrict__ mnord, unsigned* __restrict__ mxord,
    unsigned* __restrict__ hist, int* __restrict__ ccnt, float* __restrict__ psum)
{
    int bid = blockIdx.x, t = threadIdx.x;
    if (bid < 16) {                       // gram = C^T C, one (i,j) per thread
        int idx = bid * 256 + t;          // 0..4095
        int i = idx >> 6, j = idx & 63;
        float s = 0.f;
        for (int k = 0; k < D_DIM; ++k) s = fmaf(C[k*NC + i], C[k*NC + j], s);
        gram[idx] = s;
    } else if (bid < 41) {                // U = C^T W, one (i,j) per thread
        int idx = (bid - 16) * 256 + t;   // 0..6399
        int i = idx / 100, j = idx - i * 100;
        float s = 0.f;
        for (int k = 0; k < D_DIM; ++k) s = fmaf(C[k*NC + i], W[k*NCL + j], s);
        U[idx] = s;
    } else if (bid < 281) {               // pack C / [C|W] into MFMA A-frag bf16
        int b = bid - 41;                 // 0..239
        #pragma unroll
        for (int rep = 0; rep < 2; ++rep) {
            int idx = t * 2 + rep;        // 0..511 within tile
            int lane = idx >> 3, j = idx & 7;
            if (b < 64) {                 // score A: 16 kt x 4 ci
                int kt = b >> 2, ci = b & 3;
                int k = kt * 32 + (lane >> 4) * 8 + j;
                int col = ci * 16 + (lane & 15);
                PA[b * 512 + idx] = f2bf(C[k * NC + col]);
            } else {                      // ecw A: 16 kt x 11 ci (64 C + 100 W + 12 pad)
                int bb = b - 64;
                int kt = bb / 11, ci = bb % 11;
                int k = kt * 32 + (lane >> 4) * 8 + j;
                int col = ci * 16 + (lane & 15);
                float v = 0.f;
                if (col < 64) v = C[k * NC + col];
                else if (col < 164) v = W[k * NCL + (col - 64)];
                PB[bb * 512 + idx] = f2bf(v);
            }
        }
    } else if (bid < 345) {               // zero hist (64 blocks x 1024)
        int base = (bid - 281) * 1024;
        #pragma unroll
        for (int r = 0; r < 4; ++r) hist[base + r * 256 + t] = 0u;
    } else {                              // small per-concept inits
        if (t < 64) {
            mnord[t] = 0xFFFFFFFFu;
            mxord[t] = 0u;
            ccnt[t]  = 0;
            psum[t]  = 0.f;
        }
    }
}

// =================================================================================
// k2: invert+H (block 0) + scalars (block 1) + ecw (blocks 2..17) + score (18..1580).
//     Tiny serial work hides under the memory-bound score stream.
// =================================================================================
__global__ __launch_bounds__(256) void k2_main(
    const float* __restrict__ E, const float* __restrict__ Bk,
    const short* __restrict__ PA, const short* __restrict__ PB,
    const float* __restrict__ gram, const float* __restrict__ U,
    float* __restrict__ ginv, float* __restrict__ H,
    float* __restrict__ out3, float* __restrict__ T, float* __restrict__ O,
    float* __restrict__ S, float* __restrict__ Q,
    unsigned* __restrict__ mnord, unsigned* __restrict__ mxord)
{
    __shared__ float smem[64 * 65 + 64];   // 16.9 KB union
    int bid = blockIdx.x, t = threadIdx.x;

    if (bid == 0) {
        // ---- in-place Gauss-Jordan inversion of gram, then H = Ginv @ U ----
        float (*A)[65] = (float(*)[65])smem;
        float* m = smem + 64 * 65;
        for (int idx = t; idx < 4096; idx += 256) A[idx >> 6][idx & 63] = gram[idx];
        __syncthreads();
        for (int k = 0; k < 64; ++k) {
            float d = 1.0f / A[k][k];
            if (t < 64) m[t] = A[t][k];            // capture column k
            __syncthreads();
            if (t < 64 && t != k) A[k][t] *= d;    // scale row k (j != k)
            __syncthreads();
            for (int idx = t; idx < 4096; idx += 256) {
                int i = idx >> 6, j = idx & 63;
                if (i != k && j != k) A[i][j] = fmaf(-m[i], A[k][j], A[i][j]);
            }
            if (t < 64) {                          // column k + diagonal (disjoint addrs)
                if (t != k) A[t][k] = -m[t] * d;
                else        A[k][k] = d;
            }
            __syncthreads();
        }
        for (int idx = t; idx < 4096; idx += 256) ginv[idx] = A[idx >> 6][idx & 63];
        // H[k][c] = sum_l A[k][l] * U[l][c]  (A now holds the inverse)
        for (int idx = t; idx < 6400; idx += 256) {
            int k = idx / 100, c = idx - k * 100;
            float s = 0.f;
            #pragma unroll 8
            for (int l = 0; l < NC; ++l) s = fmaf(A[k][l], U[l*NCL + c], s);
            H[idx] = s;
        }
    } else if (bid == 1) {
        // ---- L_sparse_2, norm_metrics, zero L1 accumulator ----
        float* ra = smem; float* rd = smem + 256;
        float sa = 0.f, sd = 0.f;
        for (int idx = t; idx < NC * NC; idx += 256) {
            float g = gram[idx];
            sa += g;
            if (idx % (NC + 1) == 0) sd += g;
        }
        ra[t] = sa; rd[t] = sd;
        __syncthreads();
        for (int s2 = 128; s2 > 0; s2 >>= 1) {
            if (t < s2) { ra[t] += ra[t + s2]; rd[t] += rd[t + s2]; }
            __syncthreads();
        }
        if (t == 0) {
            out3[0] = 0.f;
            out3[1] = (ra[0] - rd[0]) * (1.0f / 4096.0f);
            out3[2] = rd[0] * (1.0f / 4096.0f);
        }
    } else if (bid < 18) {
        // ---- ecw: fused E@[C|W] via bf16 MFMA -> concept_pred (T), orig_pred (O) ----
        int eb = bid - 2;
        int wave = t >> 6, lane = t & 63;
        int quad = lane >> 4, l16 = lane & 15;
        int rbase = eb * 128 + wave * 32;
        int row0 = rbase + l16, row1 = rbase + 16 + l16;
        const float* p0 = E + (size_t)row0 * D_DIM + quad * 8;
        const float* p1 = E + (size_t)row1 * D_DIM + quad * 8;

        f32x4 acc[11][2];
        #pragma unroll
        for (int ci = 0; ci < 11; ++ci) { acc[ci][0] = 0.f; acc[ci][1] = 0.f; }

        for (int kt = 0; kt < 16; ++kt) {
            float4 a0 = *(const float4*)(p0 + kt*32);
            float4 b0 = *(const float4*)(p0 + kt*32 + 4);
            float4 a1 = *(const float4*)(p1 + kt*32);
            float4 b1 = *(const float4*)(p1 + kt*32 + 4);
            bf16x8 bf0 = { f2bf(a0.x), f2bf(a0.y), f2bf(a0.z), f2bf(a0.w),
                           f2bf(b0.x), f2bf(b0.y), f2bf(b0.z), f2bf(b0.w) };
            bf16x8 bf1 = { f2bf(a1.x), f2bf(a1.y), f2bf(a1.z), f2bf(a1.w),
                           f2bf(b1.x), f2bf(b1.y), f2bf(b1.z), f2bf(b1.w) };
            #pragma unroll
            for (int ci = 0; ci < 11; ++ci) {
                bf16x8 af = *(const bf16x8*)(PB + ((kt*11 + ci)*64 + lane)*8);
                acc[ci][0] = __builtin_amdgcn_mfma_f32_16x16x32_bf16(af, bf0, acc[ci][0], 0, 0, 0);
                acc[ci][1] = __builtin_amdgcn_mfma_f32_16x16x32_bf16(af, bf1, acc[ci][1], 0, 0, 0);
            }
        }
        #pragma unroll
        for (int ci = 0; ci < 11; ++ci) {
            #pragma unroll
            for (int j = 0; j < 4; ++j) {
                int col = ci*16 + quad*4 + j;
                if (col < 64) {
                    T[row0*NC + col] = acc[ci][0][j];
                    T[row1*NC + col] = acc[ci][1][j];
                } else if (col < 164) {
                    O[row0*NCL + (col-64)] = acc[ci][0][j];
                    O[row1*NCL + (col-64)] = acc[ci][1][j];
                }
            }
        }
    } else {
        // ---- score: S[c][r] = q[r] - 2 * (C^T B^T)[c][r] via bf16 MFMA ----
        int sb = bid - 18;
        unsigned* lmn = (unsigned*)smem;
        unsigned* lmx = lmn + 64;
        int wave = t >> 6, lane = t & 63;
        int quad = lane >> 4, l16 = lane & 15;
        if (t < 64) { lmn[t] = 0xFFFFFFFFu; lmx[t] = 0u; }
        __syncthreads();

        int rbase = sb * 128 + wave * 32;
        int row0 = rbase + l16, row1 = rbase + 16 + l16;
        bool v0 = row0 < NB, v1 = row1 < NB;
        int r0c = v0 ? row0 : (NB-1), r1c = v1 ? row1 : (NB-1);
        const float* p0 = Bk + (size_t)r0c * D_DIM + quad * 8;
        const float* p1 = Bk + (size_t)r1c * D_DIM + quad * 8;

        f32x4 acc[4][2];
        #pragma unroll
        for (int ci = 0; ci < 4; ++ci) { acc[ci][0] = 0.f; acc[ci][1] = 0.f; }
        float q0 = 0.f, q1 = 0.f;

        for (int kt = 0; kt < 16; ++kt) {
            float4 a0 = *(const float4*)(p0 + kt*32);
            float4 b0 = *(const float4*)(p0 + kt*32 + 4);
            float4 a1 = *(const float4*)(p1 + kt*32);
            float4 b1 = *(const float4*)(p1 + kt*32 + 4);
            q0 = fmaf(a0.x,a0.x, fmaf(a0.y,a0.y, fmaf(a0.z,a0.z, fmaf(a0.w,a0.w, q0))));
            q0 = fmaf(b0.x,b0.x, fmaf(b0.y,b0.y, fmaf(b0.z,b0.z, fmaf(b0.w,b0.w, q0))));
            q1 = fmaf(a1.x,a1.x, fmaf(a1.y,a1.y, fmaf(a1.z,a1.z, fmaf(a1.w,a1.w, q1))));
            q1 = fmaf(b1.x,b1.x, fmaf(b1.y,b1.y, fmaf(b1.z,b1.z, fmaf(b1.w,b1.w, q1))));
            bf16x8 bf0 = { f2bf(a0.x), f2bf(a0.y), f2bf(a0.z), f2bf(a0.w),
                           f2bf(b0.x), f2bf(b0.y), f2bf(b0.z), f2bf(b0.w) };
            bf16x8 bf1 = { f2bf(a1.x), f2bf(a1.y), f2bf(a1.z), f2bf(a1.w),
                           f2bf(b1.x), f2bf(b1.y), f2bf(b1.z), f2bf(b1.w) };
            #pragma unroll
            for (int ci = 0; ci < 4; ++ci) {
                bf16x8 af = *(const bf16x8*)(PA + ((kt*4 + ci)*64 + lane)*8);
                acc[ci][0] = __builtin_amdgcn_mfma_f32_16x16x32_bf16(af, bf0, acc[ci][0], 0, 0, 0);
                acc[ci][1] = __builtin_amdgcn_mfma_f32_16x16x32_bf16(af, bf1, acc[ci][1], 0, 0, 0);
            }
        }
        // q: reduce partial sums across quads (same l16)
        q0 += __shfl_xor(q0, 16); q0 += __shfl_xor(q0, 32);
        q1 += __shfl_xor(q1, 16); q1 += __shfl_xor(q1, 32);
        if (quad == 0) {
            if (v0) Q[row0] = q0;
            if (v1) Q[row1] = q1;
        }
        #pragma unroll
        for (int ci = 0; ci < 4; ++ci) {
            #pragma unroll
            for (int j = 0; j < 4; ++j) {
                int c = ci*16 + quad*4 + j;
                float s0 = q0 - 2.0f * acc[ci][0][j];
                float s1 = q1 - 2.0f * acc[ci][1][j];
                if (v0) S[(size_t)c*NB + row0] = s0;
                if (v1) S[(size_t)c*NB + row1] = s1;
                float mnv = fminf(v0 ? s0 : FLT_MAX,  v1 ? s1 : FLT_MAX);
                float mxv = fmaxf(v0 ? s0 : -FLT_MAX, v1 ? s1 : -FLT_MAX);
                #pragma unroll
                for (int o = 1; o < 16; o <<= 1) {
                    mnv = fminf(mnv, __shfl_xor(mnv, o));
                    mxv = fmaxf(mxv, __shfl_xor(mxv, o));
                }
                if (l16 == 0) {
                    atomicMin(&lmn[c], f2ord(mnv));
                    atomicMax(&lmx[c], f2ord(mxv));
                }
            }
        }
        __syncthreads();
        if (t < 64) {
            atomicMin(&mnord[t], lmn[t]);
            atomicMax(&mxord[t], lmx[t]);
        }
    }
}

// =================================================================================
// k3: ypred (blocks 0..63, H preloaded from global) + hist (blocks 64..3199).
// =================================================================================
__global__ __launch_bounds__(256) void k3_ph(
    const float* __restrict__ T, const float* __restrict__ H,
    float* __restrict__ Y,
    const float* __restrict__ S, const unsigned* __restrict__ mnord,
    const unsigned* __restrict__ mxord, unsigned* __restrict__ hist)
{
    __shared__ float smem[6400];           // H (25.6 KB) | hist bins (4 KB)
    int bid = blockIdx.x, t = threadIdx.x;
    if (bid < 64) {
        for (int idx = t; idx < 6400; idx += 256) smem[idx] = H[idx];
        __syncthreads();
        for (int o = t; o < 3200; o += 256) {
            int r = o / 100, c = o - r * 100;
            int row = bid * 32 + r;
            float s = 0.f;
            #pragma unroll 8
            for (int k = 0; k < NC; ++k) s = fmaf(T[row*NC + k], smem[k*100 + c], s);
            Y[row*NCL + c] = s;
        }
    } else {
        int h = bid - 64;
        int c = h & 63, chunk = h >> 6;    // 64 concepts x 49 chunks
        unsigned* hh = (unsigned*)smem;
        for (int i = t; i < 1024; i += 256) hh[i] = 0u;
        float mnf = ord2f(mnord[c]);
        float mxf = ord2f(mxord[c]);
        float invw = (mxf > mnf) ? 1024.0f / (mxf - mnf) : 0.f;
        __syncthreads();
        const float4* s4 = (const float4*)(S + (size_t)c * NB);
        int base = chunk * 1024;
        #pragma unroll
        for (int j = 0; j < 4; ++j) {
            int idx = base + j*256 + t;
            if (idx < NB/4) {
                float4 v = s4[idx];
                float vv[4] = {v.x, v.y, v.z, v.w};
                #pragma unroll
                for (int e = 0; e < 4; ++e) {
                    int b = (int)((vv[e] - mnf) * invw);
                    b = b < 0 ? 0 : (b > 1023 ? 1023 : b);
                    atomicAdd(&hh[b], 1u);
                }
            }
        }
        __syncthreads();
        for (int i = t; i < 1024; i += 256)
            if (hh[i]) atomicAdd(&hist[c*1024 + i], hh[i]);
    }
}

// =================================================================================
// collect: in-block scan of hist -> B; collect chunk; reduce dsum into psum.
// (scan_kernel fused; no cross-block sync — final recomputes B/nbel itself)
// =================================================================================
__global__ __launch_bounds__(256) void collect_kernel(
    const float* __restrict__ S, const float* __restrict__ Q,
    const unsigned* __restrict__ mn_ord, const unsigned* __restrict__ mx_ord,
    const unsigned* __restrict__ hist,
    int* __restrict__ ccnt, float* __restrict__ candv, float* __restrict__ candd,
    float* __restrict__ psum)
{
    __shared__ float smem[256];
    __shared__ int sB;
    int c = blockIdx.y, t = threadIdx.x;

    // ---- Phase A: derive threshold bin B from hist[c] via prefix scan ----
    {
        unsigned* sc = (unsigned*)smem;
        unsigned b4[4];
        #pragma unroll
        for (int i = 0; i < 4; ++i) b4[i] = hist[c*1024 + t*4 + i];
        unsigned ts = b4[0] + b4[1] + b4[2] + b4[3];
        sc[t] = ts;
        __syncthreads();
        for (int off = 1; off < 256; off <<= 1) {
            unsigned v = (t >= off) ? sc[t - off] : 0u;
            __syncthreads();
            sc[t] += v;
            __syncthreads();
        }
        unsigned cum = sc[t] - ts;         // exclusive prefix
        #pragma unroll
        for (int i = 0; i < 4; ++i) {
            if (cum < TK && cum + b4[i] >= TK) sB = t*4 + i;
            cum += b4[i];
        }
        __syncthreads();
    }
    int B = sB;

    // ---- Phase B: collect this chunk ----
    float mnf = ord2f(mn_ord[c]);
    float mxf = ord2f(mx_ord[c]);
    float invw = (mxf > mnf) ? 1024.0f / (mxf - mnf) : 0.f;
    const float4* s4 = (const float4*)(S + (size_t)c * NB);
    int base = blockIdx.x * 1024;
    float dsum = 0.f;
    #pragma unroll
    for (int j = 0; j < 4; ++j) {
        int idx = base + j*256 + t;
        if (idx < NB/4) {
            float4 v = s4[idx];
            float vv[4] = {v.x, v.y, v.z, v.w};
            #pragma unroll
            for (int e = 0; e < 4; ++e) {
                int b = (int)((vv[e] - mnf) * invw);
                b = b < 0 ? 0 : (b > 1023 ? 1023 : b);
                if (b < B) {
                    dsum += (Q[idx*4 + e] - vv[e]) * 0.5f;
                } else if (b == B) {
                    int p = atomicAdd(&ccnt[c], 1);
                    if (p < CAP) {
                        candv[c*CAP + p] = vv[e];
                        candd[c*CAP + p] = (Q[idx*4 + e] - vv[e]) * 0.5f;
                    }
                }
            }
        }
    }

    // ---- Phase C: block-reduce dsum into psum[c] ----
    __syncthreads();
    smem[t] = dsum;
    __syncthreads();
    for (int s2 = 128; s2 > 0; s2 >>= 1) {
        if (t < s2) smem[t] += smem[t + s2];
        __syncthreads();
    }
    if (t == 0 && smem[0] != 0.f) atomicAdd(&psum[c], smem[0]);
}

// =================================================================================
// final: recompute B/nbel from hist, then exact top-r among bin-B candidates.
// 256 threads (4 waves) per concept.
// =================================================================================
__global__ __launch_bounds__(256) void final_kernel(
    const unsigned* __restrict__ hist,
    const int* __restrict__ ccnt, const float* __restrict__ candv,
    const float* __restrict__ candd, const float* __restrict__ psum,
    float* __restrict__ out_l1)
{
    __shared__ float v[CAP];
    __shared__ float dd[CAP];
    __shared__ int sB, sNbel;
    __shared__ float rv[4]; __shared__ int ri[4];
    int c = blockIdx.x, t = threadIdx.x;
    int wave = t >> 6, lane = t & 63;

    // ---- Phase A: B and nbel from hist[c] (scan in v[] before cand load) ----
    {
        unsigned* sc = (unsigned*)v;
        unsigned b4[4];
        #pragma unroll
        for (int i = 0; i < 4; ++i) b4[i] = hist[c*1024 + t*4 + i];
        unsigned ts = b4[0] + b4[1] + b4[2] + b4[3];
        sc[t] = ts;
        __syncthreads();
        for (int off = 1; off < 256; off <<= 1) {
            unsigned x = (t >= off) ? sc[t - off] : 0u;
            __syncthreads();
            sc[t] += x;
            __syncthreads();
        }
        unsigned cum = sc[t] - ts;
        #pragma unroll
        for (int i = 0; i < 4; ++i) {
            if (cum < TK && cum + b4[i] >= TK) { sB = t*4 + i; sNbel = (int)cum; }
            cum += b4[i];
        }
        __syncthreads();
    }
    int nbel = sNbel;

    // ---- Phase B: exact top-r selection among candidates ----
    int M = ccnt[c]; if (M > CAP) M = CAP;
    int r = TK - nbel; if (r > M) r = M;
    for (int i = t; i < M; i += 256) { v[i] = candv[c*CAP + i]; dd[i] = candd[c*CAP + i]; }
    __syncthreads();
    float sum = 0.f;
    for (int j = 0; j < r; ++j) {
        float bv = FLT_MAX; int bi = -1;
        for (int i = t; i < M; i += 256)
            if (v[i] < bv) { bv = v[i]; bi = i; }
        #pragma unroll
        for (int o = 32; o > 0; o >>= 1) {
            float ov = __shfl_down(bv, o);
            int   oi = __shfl_down(bi, o);
            if (ov < bv) { bv = ov; bi = oi; }
        }
        if (lane == 0) { rv[wave] = bv; ri[wave] = bi; }
        __syncthreads();
        if (t == 0) {
            float bbv = rv[0]; int bbi = ri[0];
            #pragma unroll
            for (int w = 1; w < 4; ++w)
                if (rv[w] < bbv) { bbv = rv[w]; bbi = ri[w]; }
            if (bbi >= 0) { sum += dd[bbi]; v[bbi] = FLT_MAX; }
        }
        __syncthreads();
    }
    if (t == 0) atomicAdd(out_l1, (sum + psum[c]) * (1.0f/4096.0f));
}

extern "C" void kernel_launch(void* const* d_in, const int* in_sizes, int n_in,
                              void* d_out, int out_size, void* d_ws, size_t ws_size,
                              hipStream_t stream) {
    const float* C  = (const float*)d_in[0];   // (512, 64)
    const float* E  = (const float*)d_in[1];   // (2048, 512)
    const float* Bk = (const float*)d_in[2];   // (200000, 512)
    const float* W  = (const float*)d_in[3];   // (512, 100)
    float* out = (float*)d_out;
    float* ws  = (float*)d_ws;

    float*    gram  = ws + W_GRAM;
    float*    ginv  = ws + W_GINV;
    float*    U     = ws + W_U;
    float*    H     = ws + W_H;
    float*    Q     = ws + W_Q;
    unsigned* mnord = (unsigned*)(ws + W_MIN);
    unsigned* mxord = (unsigned*)(ws + W_MAX);
    int*      ccnt  = (int*)(ws + W_CCNT);
    float*    psum  = ws + W_PSUM;
    unsigned* hist  = (unsigned*)(ws + W_HIST);
    float*    candv = ws + W_CANDV;
    float*    candd = ws + W_CANDD;
    short*    PA    = (short*)(ws + W_PACKA);
    short*    PB    = (short*)(ws + W_PACKB);
    float*    S     = ws + W_S;

    // 5 dispatches (was 6 in R1; no cross-block fences anywhere)
    k1_setup<<<346, 256, 0, stream>>>(C, W, PA, PB, gram, U, mnord, mxord, hist, ccnt, psum);
    k2_main <<<1581, 256, 0, stream>>>(E, Bk, PA, PB, gram, U, ginv, H, out + O_L1,
                                       out + O_CPRED, out + O_ORIG, S, Q, mnord, mxord);
    k3_ph   <<<3200, 256, 0, stream>>>(out + O_CPRED, H, out + O_YPRED,
                                       S, mnord, mxord, hist);
    collect_kernel<<<dim3(49, 64), 256, 0, stream>>>(S, Q, mnord, mxord, hist,
                                                     ccnt, candv, candd, psum);
    final_kernel  <<<NC, 256, 0, stream>>>(hist, ccnt, candv, candd, psum, out + O_L1);
}